// Round 1
// baseline (1957.958 us; speedup 1.0000x reference)
//
#include <hip/hip_runtime.h>

#define DIM 64

// ---- float -> order-preserving unsigned mapping (for atomicMax on floats) ----
__device__ __forceinline__ unsigned int f2u_ord(float f) {
    unsigned int b = __float_as_uint(f);
    return (b & 0x80000000u) ? ~b : (b | 0x80000000u);
}
__device__ __forceinline__ float u2f_ord(unsigned int k) {
    unsigned int b = (k & 0x80000000u) ? (k & 0x7FFFFFFFu) : ~k;
    return __uint_as_float(b);
}

// ---- Pass 1a: per-edge score = dot(ent[tail], rel[etype-1]) / 8, atomicMax per head segment ----
__global__ __launch_bounds__(256) void score_edges(
    const float* __restrict__ ent, const float* __restrict__ rel,
    const int* __restrict__ head, const int* __restrict__ tail,
    const int* __restrict__ etype, float* __restrict__ score,
    unsigned int* __restrict__ smax, int E) {
    int t = blockIdx.x * blockDim.x + threadIdx.x;
    int e = t >> 4, l = t & 15;            // 16 lanes per edge, float4 each
    if (e >= E) return;
    const float4 a = ((const float4*)(ent + (size_t)tail[e] * DIM))[l];
    const float4 b = ((const float4*)(rel + (size_t)(etype[e] - 1) * DIM))[l];
    float s = a.x * b.x + a.y * b.y + a.z * b.z + a.w * b.w;
    s += __shfl_xor(s, 1);
    s += __shfl_xor(s, 2);
    s += __shfl_xor(s, 4);
    s += __shfl_xor(s, 8);
    if (l == 0) {
        s *= 0.125f;
        score[e] = s;
        atomicMax(&smax[head[e]], f2u_ord(s));
    }
}

// ---- Pass 1b: per-interaction score = sum_d inter[t][d]*user[u][d]*ent[item][d] ----
__global__ __launch_bounds__(256) void score_inter(
    const float* __restrict__ ent, const float* __restrict__ usr,
    const float* __restrict__ itc,
    const int* __restrict__ uidx, const int* __restrict__ iidx,
    const int* __restrict__ ttype, float* __restrict__ score,
    unsigned int* __restrict__ smax, int I) {
    int t = blockIdx.x * blockDim.x + threadIdx.x;
    int e = t >> 4, l = t & 15;
    if (e >= I) return;
    const float4 a = ((const float4*)(ent + (size_t)iidx[e] * DIM))[l];
    const float4 b = ((const float4*)(usr + (size_t)uidx[e] * DIM))[l];
    const float4 c = ((const float4*)(itc + (size_t)ttype[e] * DIM))[l];
    float s = a.x * b.x * c.x + a.y * b.y * c.y + a.z * b.z * c.z + a.w * b.w * c.w;
    s += __shfl_xor(s, 1);
    s += __shfl_xor(s, 2);
    s += __shfl_xor(s, 4);
    s += __shfl_xor(s, 8);
    if (l == 0) {
        score[e] = s;
        atomicMax(&smax[uidx[e]], f2u_ord(s));
    }
}

// ---- Pass 2 (generic): e = exp(score - max[seg]); atomicAdd(sum[seg], e) ----
__global__ __launch_bounds__(256) void expsum(
    const int* __restrict__ seg, float* __restrict__ score,
    const unsigned int* __restrict__ smax, float* __restrict__ ssum, int N) {
    int e = blockIdx.x * blockDim.x + threadIdx.x;
    if (e >= N) return;
    int h = seg[e];
    float ee = __expf(score[e] - u2f_ord(smax[h]));
    score[e] = ee;                          // overwrite in place
    atomicAdd(&ssum[h], ee);
}

// ---- Pass 3 (generic): w = e/sum[seg]; write w; agg[seg] += w * src_emb[src] ----
__global__ __launch_bounds__(256) void seg_agg(
    const float* __restrict__ src_emb,
    const int* __restrict__ seg, const int* __restrict__ src,
    const float* __restrict__ ee, const float* __restrict__ ssum,
    float* __restrict__ w_out, float* __restrict__ agg, int N) {
    int t = blockIdx.x * blockDim.x + threadIdx.x;
    int e = t >> 4, l = t & 15;
    if (e >= N) return;
    int h = seg[e];
    float w = ee[e] / ssum[h];
    if (l == 0) w_out[e] = w;
    const float4 a = ((const float4*)(src_emb + (size_t)src[e] * DIM))[l];
    float* dst = agg + (size_t)h * DIM + l * 4;
    atomicAdd(dst + 0, a.x * w);
    atomicAdd(dst + 1, a.y * w);
    atomicAdd(dst + 2, a.z * w);
    atomicAdd(dst + 3, a.w * w);
}

extern "C" void kernel_launch(void* const* d_in, const int* in_sizes, int n_in,
                              void* d_out, int out_size, void* d_ws, size_t ws_size,
                              hipStream_t stream) {
    const float* ent  = (const float*)d_in[0];
    const float* usr  = (const float*)d_in[1];
    const float* itc  = (const float*)d_in[2];
    const float* rel  = (const float*)d_in[3];
    const int* eidx   = (const int*)d_in[4];
    const int* etype  = (const int*)d_in[5];
    const int* uidx   = (const int*)d_in[6];
    const int* iidx   = (const int*)d_in[7];
    const int* ttype  = (const int*)d_in[8];

    const int E  = in_sizes[4] / 2;
    const int I  = in_sizes[6];
    const int nE = in_sizes[0] / DIM;
    const int nU = in_sizes[1] / DIM;
    const int* head = eidx;
    const int* tail = eidx + E;

    float* out_entity = (float*)d_out;
    float* out_user   = out_entity + (size_t)nE * DIM;
    float* out_attw   = out_user + (size_t)nU * DIM;
    float* out_w1     = out_attw + I;

    // workspace layout (floats/uints)
    float* e_sc        = (float*)d_ws;                 // E
    float* i_sc        = e_sc + E;                     // I
    unsigned int* e_mx = (unsigned int*)(i_sc + I);    // nE
    float* e_sm        = (float*)(e_mx + nE);          // nE
    unsigned int* u_mx = (unsigned int*)(e_sm + nE);   // nU
    float* u_sm        = (float*)(u_mx + nU);          // nU

    // zero agg outputs (harness poisons d_out) and max/sum accumulators
    hipMemsetAsync(d_out, 0, (size_t)(nE + nU) * DIM * sizeof(float), stream);
    hipMemsetAsync(e_mx, 0, (size_t)(2 * nE + 2 * nU) * sizeof(unsigned int), stream);

    const int T = 256;
    dim3 gE16((unsigned)((E * 16 + T - 1) / T));
    dim3 gE((unsigned)((E + T - 1) / T));
    dim3 gI16((unsigned)((I * 16 + T - 1) / T));
    dim3 gI((unsigned)((I + T - 1) / T));

    // entity pipeline
    score_edges<<<gE16, T, 0, stream>>>(ent, rel, head, tail, etype, e_sc, e_mx, E);
    expsum<<<gE, T, 0, stream>>>(head, e_sc, e_mx, e_sm, E);
    seg_agg<<<gE16, T, 0, stream>>>(ent, head, tail, e_sc, e_sm, out_w1, out_entity, E);

    // user pipeline
    score_inter<<<gI16, T, 0, stream>>>(ent, usr, itc, uidx, iidx, ttype, i_sc, u_mx, I);
    expsum<<<gI, T, 0, stream>>>(uidx, i_sc, u_mx, u_sm, I);
    seg_agg<<<gI16, T, 0, stream>>>(ent, uidx, iidx, i_sc, u_sm, out_attw, out_user, I);
}

// Round 2
// 604.342 us; speedup vs baseline: 3.2398x; 3.2398x over previous
//
#include <hip/hip_runtime.h>

#define DIM 64
#define SCAN_B 512

// ---- Pass 1a: per-edge score = dot(ent[tail], rel[etype-1]) / 8 ; count segment degree ----
__global__ __launch_bounds__(256) void score_edges(
    const float* __restrict__ ent, const float* __restrict__ rel,
    const int* __restrict__ head, const int* __restrict__ tail,
    const int* __restrict__ etype, float* __restrict__ score,
    unsigned int* __restrict__ deg, int E) {
    int t = blockIdx.x * blockDim.x + threadIdx.x;
    int e = t >> 4, l = t & 15;            // 16 lanes per edge, float4 each
    if (e >= E) return;
    const float4 a = ((const float4*)(ent + (size_t)tail[e] * DIM))[l];
    const float4 b = ((const float4*)(rel + (size_t)(etype[e] - 1) * DIM))[l];
    float s = a.x * b.x + a.y * b.y + a.z * b.z + a.w * b.w;
    s += __shfl_xor(s, 1);
    s += __shfl_xor(s, 2);
    s += __shfl_xor(s, 4);
    s += __shfl_xor(s, 8);
    if (l == 0) {
        score[e] = s * 0.125f;
        atomicAdd(&deg[head[e]], 1u);
    }
}

// ---- Pass 1b: per-interaction score = sum_d inter[t][d]*user[u][d]*ent[item][d] ; degree ----
__global__ __launch_bounds__(256) void score_inter(
    const float* __restrict__ ent, const float* __restrict__ usr,
    const float* __restrict__ itc,
    const int* __restrict__ uidx, const int* __restrict__ iidx,
    const int* __restrict__ ttype, float* __restrict__ score,
    unsigned int* __restrict__ deg, int I, int nE) {
    int t = blockIdx.x * blockDim.x + threadIdx.x;
    int e = t >> 4, l = t & 15;
    if (e >= I) return;
    const float4 a = ((const float4*)(ent + (size_t)iidx[e] * DIM))[l];
    const float4 b = ((const float4*)(usr + (size_t)uidx[e] * DIM))[l];
    const float4 c = ((const float4*)(itc + (size_t)ttype[e] * DIM))[l];
    float s = a.x * b.x * c.x + a.y * b.y * c.y + a.z * b.z * c.z + a.w * b.w * c.w;
    s += __shfl_xor(s, 1);
    s += __shfl_xor(s, 2);
    s += __shfl_xor(s, 4);
    s += __shfl_xor(s, 8);
    if (l == 0) {
        score[e] = s;
        atomicAdd(&deg[nE + uidx[e]], 1u);
    }
}

// ---- Scan step 1: per-block reduction of deg ----
__global__ __launch_bounds__(SCAN_B) void scan_partial(
    const unsigned int* __restrict__ deg, unsigned int* __restrict__ part, int n) {
    __shared__ unsigned int lds[SCAN_B];
    int i = blockIdx.x * SCAN_B + threadIdx.x;
    lds[threadIdx.x] = (i < n) ? deg[i] : 0u;
    __syncthreads();
    for (int off = SCAN_B >> 1; off > 0; off >>= 1) {
        if (threadIdx.x < off) lds[threadIdx.x] += lds[threadIdx.x + off];
        __syncthreads();
    }
    if (threadIdx.x == 0) part[blockIdx.x] = lds[0];
}

// ---- Scan step 2: single-block exclusive scan of block partials (nb <= 1024) ----
__global__ __launch_bounds__(1024) void scan_block(unsigned int* __restrict__ part, int nb) {
    __shared__ unsigned int lds[1024];
    int t = threadIdx.x;
    unsigned int v = (t < nb) ? part[t] : 0u;
    lds[t] = v;
    __syncthreads();
    for (int off = 1; off < 1024; off <<= 1) {
        unsigned int x = (t >= off) ? lds[t - off] : 0u;
        __syncthreads();
        lds[t] += x;
        __syncthreads();
    }
    if (t < nb) part[t] = lds[t] - v;   // exclusive prefix of partials
}

// ---- Scan step 3: in-block exclusive scan + block offset -> offsets, cursor copy ----
__global__ __launch_bounds__(SCAN_B) void scan_final(
    const unsigned int* __restrict__ deg, const unsigned int* __restrict__ part,
    unsigned int* __restrict__ offs, unsigned int* __restrict__ cur, int n) {
    __shared__ unsigned int lds[SCAN_B];
    int t = threadIdx.x;
    int i = blockIdx.x * SCAN_B + t;
    unsigned int v = (i < n) ? deg[i] : 0u;
    lds[t] = v;
    __syncthreads();
    for (int off = 1; off < SCAN_B; off <<= 1) {
        unsigned int x = (t >= off) ? lds[t - off] : 0u;
        __syncthreads();
        lds[t] += x;
        __syncthreads();
    }
    if (i < n) {
        unsigned int o = part[blockIdx.x] + lds[t] - v;
        offs[i] = o;
        cur[i] = o;
    }
}

// ---- Scatter: counting-sort edge ids into per-segment lists ----
__global__ __launch_bounds__(256) void scatter_ids(
    const int* __restrict__ head, const int* __restrict__ uidx,
    unsigned int* __restrict__ cur, int* __restrict__ elist,
    int E, int I, int nE) {
    int t = blockIdx.x * blockDim.x + threadIdx.x;
    if (t < E) {
        unsigned int p = atomicAdd(&cur[head[t]], 1u);
        elist[p] = t;
    } else if (t < E + I) {
        int e = t - E;
        unsigned int p = atomicAdd(&cur[nE + uidx[e]], 1u);
        elist[p] = e;
    }
}

// ---- Fused per-segment softmax + weighted gather-accumulate (16 lanes / segment) ----
__global__ __launch_bounds__(256) void seg_softmax_agg(
    const float* __restrict__ src_emb, const int* __restrict__ src_idx,
    const float* __restrict__ score, const int* __restrict__ elist,
    const unsigned int* __restrict__ deg, const unsigned int* __restrict__ offs,
    int segbase, float* __restrict__ w_out, float* __restrict__ agg, int nSeg) {
    int t = blockIdx.x * blockDim.x + threadIdx.x;
    int h = t >> 4, l = t & 15;
    if (h >= nSeg) return;
    unsigned int d = deg[segbase + h];
    float4 acc = make_float4(0.f, 0.f, 0.f, 0.f);
    if (d) {
        unsigned int off = offs[segbase + h];
        float m = -3.0e38f;
        for (unsigned int j = 0; j < d; j++) m = fmaxf(m, score[elist[off + j]]);
        float s = 0.f;
        for (unsigned int j = 0; j < d; j++) s += __expf(score[elist[off + j]] - m);
        float inv = 1.0f / s;
        for (unsigned int j = 0; j < d; j++) {
            int e = elist[off + j];
            float w = __expf(score[e] - m) * inv;
            if (l == 0) w_out[e] = w;
            const float4 a = ((const float4*)(src_emb + (size_t)src_idx[e] * DIM))[l];
            acc.x += w * a.x; acc.y += w * a.y; acc.z += w * a.z; acc.w += w * a.w;
        }
    }
    ((float4*)(agg + (size_t)h * DIM))[l] = acc;
}

extern "C" void kernel_launch(void* const* d_in, const int* in_sizes, int n_in,
                              void* d_out, int out_size, void* d_ws, size_t ws_size,
                              hipStream_t stream) {
    const float* ent  = (const float*)d_in[0];
    const float* usr  = (const float*)d_in[1];
    const float* itc  = (const float*)d_in[2];
    const float* rel  = (const float*)d_in[3];
    const int* eidx   = (const int*)d_in[4];
    const int* etype  = (const int*)d_in[5];
    const int* uidx   = (const int*)d_in[6];
    const int* iidx   = (const int*)d_in[7];
    const int* ttype  = (const int*)d_in[8];

    const int E  = in_sizes[4] / 2;
    const int I  = in_sizes[6];
    const int nE = in_sizes[0] / DIM;
    const int nU = in_sizes[1] / DIM;
    const int* head = eidx;
    const int* tail = eidx + E;
    const int NSEG = nE + nU;
    const int NB = (NSEG + SCAN_B - 1) / SCAN_B;   // 586 <= 1024

    float* out_entity = (float*)d_out;
    float* out_user   = out_entity + (size_t)nE * DIM;
    float* out_attw   = out_user + (size_t)nU * DIM;
    float* out_w1     = out_attw + I;

    // workspace layout
    float* e_sc        = (float*)d_ws;                    // E floats
    float* i_sc        = e_sc + E;                        // I floats
    unsigned int* deg  = (unsigned int*)(i_sc + I);       // NSEG
    unsigned int* offs = deg + NSEG;                      // NSEG
    unsigned int* cur  = offs + NSEG;                     // NSEG
    unsigned int* part = cur + NSEG;                      // NB (<=1024)
    int* elist         = (int*)(part + 1024);             // E + I

    hipMemsetAsync(deg, 0, (size_t)NSEG * sizeof(unsigned int), stream);

    const int T = 256;
    dim3 gE16((unsigned)((E * 16 + T - 1) / T));
    dim3 gI16((unsigned)((I * 16 + T - 1) / T));
    dim3 gEI((unsigned)((E + I + T - 1) / T));

    // scores + degree histogram
    score_edges<<<gE16, T, 0, stream>>>(ent, rel, head, tail, etype, e_sc, deg, E);
    score_inter<<<gI16, T, 0, stream>>>(ent, usr, itc, uidx, iidx, ttype, i_sc, deg, I, nE);

    // exclusive scan of 300K degrees -> CSR offsets
    scan_partial<<<dim3((unsigned)NB), SCAN_B, 0, stream>>>(deg, part, NSEG);
    scan_block<<<dim3(1), 1024, 0, stream>>>(part, NB);
    scan_final<<<dim3((unsigned)NB), SCAN_B, 0, stream>>>(deg, part, offs, cur, NSEG);

    // counting-sort edge/interaction ids into segment lists
    scatter_ids<<<gEI, T, 0, stream>>>(head, uidx, cur, elist, E, I, nE);

    // fused softmax + aggregate (gather-style, no atomics)
    dim3 gAE((unsigned)(((size_t)nE * 16 + T - 1) / T));
    dim3 gAU((unsigned)(((size_t)nU * 16 + T - 1) / T));
    seg_softmax_agg<<<gAE, T, 0, stream>>>(ent, tail, e_sc, elist, deg, offs,
                                           0, out_w1, out_entity, nE);
    seg_softmax_agg<<<gAU, T, 0, stream>>>(ent, iidx, i_sc, elist, deg, offs,
                                           nE, out_attw, out_user, nU);
}

// Round 3
// 353.016 us; speedup vs baseline: 5.5464x; 1.7119x over previous
//
#include <hip/hip_runtime.h>

#define DIM 64
#define SCAN_B 512

// ---- Pass 1a: per-edge score = dot(ent[tail], rel[etype-1]) / 8 ; degree + rank ----
__global__ __launch_bounds__(256) void score_edges(
    const float* __restrict__ ent, const float* __restrict__ rel,
    const int* __restrict__ head, const int* __restrict__ tail,
    const int* __restrict__ etype, float* __restrict__ score,
    unsigned int* __restrict__ deg, unsigned int* __restrict__ rank, int E) {
    int t = blockIdx.x * blockDim.x + threadIdx.x;
    int e = t >> 4, l = t & 15;            // 16 lanes per edge, float4 each
    if (e >= E) return;
    const float4 a = ((const float4*)(ent + (size_t)tail[e] * DIM))[l];
    const float4 b = ((const float4*)(rel + (size_t)(etype[e] - 1) * DIM))[l];
    float s = a.x * b.x + a.y * b.y + a.z * b.z + a.w * b.w;
    s += __shfl_xor(s, 1);
    s += __shfl_xor(s, 2);
    s += __shfl_xor(s, 4);
    s += __shfl_xor(s, 8);
    if (l == 0) {
        score[e] = s * 0.125f;
        rank[e] = atomicAdd(&deg[head[e]], 1u);
    }
}

// ---- Pass 1b: per-interaction score ; degree + rank ----
__global__ __launch_bounds__(256) void score_inter(
    const float* __restrict__ ent, const float* __restrict__ usr,
    const float* __restrict__ itc,
    const int* __restrict__ uidx, const int* __restrict__ iidx,
    const int* __restrict__ ttype, float* __restrict__ score,
    unsigned int* __restrict__ deg, unsigned int* __restrict__ rank, int I, int nE) {
    int t = blockIdx.x * blockDim.x + threadIdx.x;
    int e = t >> 4, l = t & 15;
    if (e >= I) return;
    const float4 a = ((const float4*)(ent + (size_t)iidx[e] * DIM))[l];
    const float4 b = ((const float4*)(usr + (size_t)uidx[e] * DIM))[l];
    const float4 c = ((const float4*)(itc + (size_t)ttype[e] * DIM))[l];
    float s = a.x * b.x * c.x + a.y * b.y * c.y + a.z * b.z * c.z + a.w * b.w * c.w;
    s += __shfl_xor(s, 1);
    s += __shfl_xor(s, 2);
    s += __shfl_xor(s, 4);
    s += __shfl_xor(s, 8);
    if (l == 0) {
        score[e] = s;
        rank[e] = atomicAdd(&deg[nE + uidx[e]], 1u);
    }
}

// ---- Scan step 1: per-block reduction of deg ----
__global__ __launch_bounds__(SCAN_B) void scan_partial(
    const unsigned int* __restrict__ deg, unsigned int* __restrict__ part, int n) {
    __shared__ unsigned int lds[SCAN_B];
    int i = blockIdx.x * SCAN_B + threadIdx.x;
    lds[threadIdx.x] = (i < n) ? deg[i] : 0u;
    __syncthreads();
    for (int off = SCAN_B >> 1; off > 0; off >>= 1) {
        if (threadIdx.x < off) lds[threadIdx.x] += lds[threadIdx.x + off];
        __syncthreads();
    }
    if (threadIdx.x == 0) part[blockIdx.x] = lds[0];
}

// ---- Scan step 2: single-block exclusive scan of block partials (nb <= 1024) ----
__global__ __launch_bounds__(1024) void scan_block(unsigned int* __restrict__ part, int nb) {
    __shared__ unsigned int lds[1024];
    int t = threadIdx.x;
    unsigned int v = (t < nb) ? part[t] : 0u;
    lds[t] = v;
    __syncthreads();
    for (int off = 1; off < 1024; off <<= 1) {
        unsigned int x = (t >= off) ? lds[t - off] : 0u;
        __syncthreads();
        lds[t] += x;
        __syncthreads();
    }
    if (t < nb) part[t] = lds[t] - v;   // exclusive prefix of partials
}

// ---- Scan step 3: in-block exclusive scan + block offset -> offsets ----
__global__ __launch_bounds__(SCAN_B) void scan_final(
    const unsigned int* __restrict__ deg, const unsigned int* __restrict__ part,
    unsigned int* __restrict__ offs, int n) {
    __shared__ unsigned int lds[SCAN_B];
    int t = threadIdx.x;
    int i = blockIdx.x * SCAN_B + t;
    unsigned int v = (i < n) ? deg[i] : 0u;
    lds[t] = v;
    __syncthreads();
    for (int off = 1; off < SCAN_B; off <<= 1) {
        unsigned int x = (t >= off) ? lds[t - off] : 0u;
        __syncthreads();
        lds[t] += x;
        __syncthreads();
    }
    if (i < n) offs[i] = part[blockIdx.x] + lds[t] - v;
}

// ---- Scatter (atomic-free): pay[offs[seg]+rank] = {src_idx, score} as packed u64 ----
__global__ __launch_bounds__(256) void scatter_pay(
    const int* __restrict__ head, const int* __restrict__ tail,
    const int* __restrict__ uidx, const int* __restrict__ iidx,
    const float* __restrict__ e_sc, const float* __restrict__ i_sc,
    const unsigned int* __restrict__ rank_e, const unsigned int* __restrict__ rank_i,
    const unsigned int* __restrict__ offs, unsigned long long* __restrict__ pay,
    int E, int I, int nE) {
    int t = blockIdx.x * blockDim.x + threadIdx.x;
    if (t < E) {
        unsigned int p = offs[head[t]] + rank_e[t];
        unsigned long long v = ((unsigned long long)(unsigned int)__float_as_int(e_sc[t]) << 32)
                             | (unsigned int)tail[t];
        __builtin_nontemporal_store(v, &pay[p]);
    } else if (t < E + I) {
        int e = t - E;
        unsigned int p = offs[nE + uidx[e]] + rank_i[e];
        unsigned long long v = ((unsigned long long)(unsigned int)__float_as_int(i_sc[e]) << 32)
                             | (unsigned int)iidx[e];
        __builtin_nontemporal_store(v, &pay[p]);
    }
}

// ---- Fused per-segment softmax + weighted gather-accumulate (16 lanes / segment) ----
__global__ __launch_bounds__(256) void seg_softmax_agg(
    const float* __restrict__ emb, const unsigned long long* __restrict__ pay,
    const unsigned int* __restrict__ deg, const unsigned int* __restrict__ offs,
    int segbase, float2* __restrict__ msum, float* __restrict__ agg, int nSeg) {
    int t = blockIdx.x * blockDim.x + threadIdx.x;
    int h = t >> 4, l = t & 15;
    if (h >= nSeg) return;
    unsigned int d = deg[segbase + h];
    float4 acc = make_float4(0.f, 0.f, 0.f, 0.f);
    float m = -3.0e38f, inv = 0.f;
    if (d) {
        unsigned int off = offs[segbase + h];
        // per-lane partial max over r = l, l+16, ... (coalesced pay reads)
        for (unsigned int r = l; r < d; r += 16)
            m = fmaxf(m, __int_as_float((int)(pay[off + r] >> 32)));
        m = fmaxf(m, __shfl_xor(m, 1));
        m = fmaxf(m, __shfl_xor(m, 2));
        m = fmaxf(m, __shfl_xor(m, 4));
        m = fmaxf(m, __shfl_xor(m, 8));
        // per-lane partial sum of exp
        float s = 0.f;
        for (unsigned int r = l; r < d; r += 16)
            s += __expf(__int_as_float((int)(pay[off + r] >> 32)) - m);
        s += __shfl_xor(s, 1);
        s += __shfl_xor(s, 2);
        s += __shfl_xor(s, 4);
        s += __shfl_xor(s, 8);
        inv = 1.0f / s;
        // weighted row accumulation: pay[off+j] same addr across lanes -> broadcast
        for (unsigned int j = 0; j < d; j++) {
            unsigned long long v = pay[off + j];
            int src = (int)(v & 0xffffffffu);
            float w = __expf(__int_as_float((int)(v >> 32)) - m) * inv;
            const float4 a = ((const float4*)(emb + (size_t)src * DIM))[l];
            acc.x += w * a.x; acc.y += w * a.y; acc.z += w * a.z; acc.w += w * a.w;
        }
    }
    if (l == 0) msum[segbase + h] = make_float2(m, inv);
    ((float4*)(agg + (size_t)h * DIM))[l] = acc;
}

// ---- Epilogue: coalesced per-edge weight writes ----
__global__ __launch_bounds__(256) void wout(
    const int* __restrict__ head, const int* __restrict__ uidx,
    const float* __restrict__ e_sc, const float* __restrict__ i_sc,
    const float2* __restrict__ msum,
    float* __restrict__ w1, float* __restrict__ attw, int E, int I, int nE) {
    int t = blockIdx.x * blockDim.x + threadIdx.x;
    if (t < E) {
        float2 mi = msum[head[t]];
        w1[t] = __expf(e_sc[t] - mi.x) * mi.y;
    } else if (t < E + I) {
        int e = t - E;
        float2 mi = msum[nE + uidx[e]];
        attw[e] = __expf(i_sc[e] - mi.x) * mi.y;
    }
}

extern "C" void kernel_launch(void* const* d_in, const int* in_sizes, int n_in,
                              void* d_out, int out_size, void* d_ws, size_t ws_size,
                              hipStream_t stream) {
    const float* ent  = (const float*)d_in[0];
    const float* usr  = (const float*)d_in[1];
    const float* itc  = (const float*)d_in[2];
    const float* rel  = (const float*)d_in[3];
    const int* eidx   = (const int*)d_in[4];
    const int* etype  = (const int*)d_in[5];
    const int* uidx   = (const int*)d_in[6];
    const int* iidx   = (const int*)d_in[7];
    const int* ttype  = (const int*)d_in[8];

    const int E  = in_sizes[4] / 2;
    const int I  = in_sizes[6];
    const int nE = in_sizes[0] / DIM;
    const int nU = in_sizes[1] / DIM;
    const int* head = eidx;
    const int* tail = eidx + E;
    const int NSEG = nE + nU;
    const int NB = (NSEG + SCAN_B - 1) / SCAN_B;   // 586 <= 1024

    float* out_entity = (float*)d_out;
    float* out_user   = out_entity + (size_t)nE * DIM;
    float* out_attw   = out_user + (size_t)nU * DIM;
    float* out_w1     = out_attw + I;

    // workspace layout (all offsets 8B-aligned by construction)
    float* e_sc          = (float*)d_ws;                    // E
    float* i_sc          = e_sc + E;                        // I
    unsigned int* rank_e = (unsigned int*)(i_sc + I);       // E
    unsigned int* rank_i = rank_e + E;                      // I
    unsigned int* deg    = rank_i + I;                      // NSEG
    unsigned int* offs   = deg + NSEG;                      // NSEG
    unsigned int* part   = offs + NSEG;                     // 1024
    float2* msum         = (float2*)(part + 1024);          // NSEG
    unsigned long long* pay = (unsigned long long*)(msum + NSEG); // E + I

    hipMemsetAsync(deg, 0, (size_t)NSEG * sizeof(unsigned int), stream);

    const int T = 256;
    dim3 gE16((unsigned)((E * 16 + T - 1) / T));
    dim3 gI16((unsigned)((I * 16 + T - 1) / T));
    dim3 gEI((unsigned)((E + I + T - 1) / T));

    // scores + degree histogram + stable ranks
    score_edges<<<gE16, T, 0, stream>>>(ent, rel, head, tail, etype, e_sc, deg, rank_e, E);
    score_inter<<<gI16, T, 0, stream>>>(ent, usr, itc, uidx, iidx, ttype, i_sc, deg, rank_i, I, nE);

    // exclusive scan of 300K degrees -> CSR offsets
    scan_partial<<<dim3((unsigned)NB), SCAN_B, 0, stream>>>(deg, part, NSEG);
    scan_block<<<dim3(1), 1024, 0, stream>>>(part, NB);
    scan_final<<<dim3((unsigned)NB), SCAN_B, 0, stream>>>(deg, part, offs, NSEG);

    // atomic-free scatter of (score, src_idx) payloads
    scatter_pay<<<gEI, T, 0, stream>>>(head, tail, uidx, iidx, e_sc, i_sc,
                                       rank_e, rank_i, offs, pay, E, I, nE);

    // fused softmax + aggregate (gather-style, no atomics)
    dim3 gAE((unsigned)(((size_t)nE * 16 + T - 1) / T));
    dim3 gAU((unsigned)(((size_t)nU * 16 + T - 1) / T));
    seg_softmax_agg<<<gAE, T, 0, stream>>>(ent, pay, deg, offs, 0, msum, out_entity, nE);
    seg_softmax_agg<<<gAU, T, 0, stream>>>(ent, pay, deg, offs, nE, msum, out_user, nU);

    // coalesced per-edge weights
    wout<<<gEI, T, 0, stream>>>(head, uidx, e_sc, i_sc, msum, out_w1, out_attw, E, I, nE);
}